// Round 5
// baseline (160.571 us; speedup 1.0000x reference)
//
#include <hip/hip_runtime.h>

// GNNCriticEncoder fused kernel v7 (MI355X / gfx950)
// v6 diagnosis: latency-bound, ~70 cyc/instruction, all pipes idle (MFMA 6%, VALU 25%,
// HBM 2%). Occupancy structurally capped at 4 waves/SIMD by 9KB LDS per item-wave.
// v7: TWO waves per item (head-split: each wave owns 2 heads / 64 e-rows / 4 m-tiles).
//  - GAT splits cleanly by head: GEMM mt, alpha, softmax, PV, pool all wave-local.
//  - hT halves wave-private, HSTR=40 (80B rows: 16B-aligned, conflict-free b128 reads).
//  - x <-> hT alias (never coexist) -> item tile 10240 B; pool via direct global
//    stores -> LDS 20480 B/block = EXACTLY 8 blocks/CU = 32 waves/CU (2x v6).
//  - per-wave critical chain halved. Latency-bound => expect ~1.6-1.9x.
// ws = exactly 81920 B (do not exceed).

#define NTOK 32
#define EMB  128
#define OBSL 1056
#define XSTR 136   // x row stride in shorts (272 B, 16B-aligned rows)
#define HSTR 40    // hT row stride in shorts (80 B: 16B-aligned, 20 words % 32 -> 2-way max)
#define TILE 5120  // shorts per item tile = max(x 32*136=4352, hT 2*64*40=5120)

typedef __attribute__((ext_vector_type(8))) short  short8;   // 8 x bf16 MFMA A/B frag
typedef __attribute__((ext_vector_type(4))) float  floatx4;  // MFMA C/D frag
typedef __attribute__((ext_vector_type(2))) unsigned uint2v;

__device__ __forceinline__ short f2bf(float f) {             // scalar RNE (prep kernel only)
  union { float f; unsigned u; } v; v.f = f;
  unsigned r = (v.u + 0x7fffu + ((v.u >> 16) & 1u)) >> 16;
  return (short)(unsigned short)r;
}
// HW packed fp32->bf16 (RNE): plain VALU op, safe in inline asm
__device__ __forceinline__ unsigned pk2(float a, float b) {
  unsigned r; asm("v_cvt_pk_bf16_f32 %0, %1, %2" : "=v"(r) : "v"(a), "v"(b)); return r;
}
__device__ __forceinline__ float exp2_hw(float x) {
#if __has_builtin(__builtin_amdgcn_exp2f)
  return __builtin_amdgcn_exp2f(x);
#else
  return exp2f(x);
#endif
}
__device__ __forceinline__ float rcp_hw(float x) {
#if __has_builtin(__builtin_amdgcn_rcpf)
  return __builtin_amdgcn_rcpf(x);
#else
  return 1.0f / x;
#endif
}
__device__ __forceinline__ float elu1(float v) { return v > 0.f ? v : __expf(v) - 1.f; }
__device__ __forceinline__ floatx4 mfma16(short8 a, short8 b, floatx4 c) {
  return __builtin_amdgcn_mfma_f32_16x16x32_bf16(a, b, c, 0, 0, 0);
}

// ws layout (bf16): [0,8192) embT[e][k] (k<40 Wv, else Wp) | [8192,24576) wT0[e][k] | [24576,40960) wT1[e][k]
// Total: 40960 shorts = exactly 81920 B. DO NOT EXCEED (ws_size appears to be 80 KiB).
__global__ void prep_weights(const float* __restrict__ Wv, const float* __restrict__ Wp,
                             const float* __restrict__ w0, const float* __restrict__ w1,
                             short* __restrict__ ws) {
  int idx = blockIdx.x * 256 + threadIdx.x;          // 160 blocks x 256 = 40960
  if (idx < 8192) {
    int e = idx >> 6, k = idx & 63;
    float v = (k < 40) ? Wv[(size_t)k * EMB + e] : Wp[(size_t)(k - 40) * EMB + e];
    ws[idx] = f2bf(v);
  } else if (idx < 24576) {
    int t = idx - 8192; int e = t >> 7, k = t & 127;
    ws[idx] = f2bf(w0[(size_t)k * EMB + e]);
  } else {
    int t = idx - 24576; int e = t >> 7, k = t & 127;
    ws[idx] = f2bf(w1[(size_t)k * EMB + e]);
  }
}

__global__ __launch_bounds__(256, 8) void gnn_fused(
    const float* __restrict__ obs,
    const float* __restrict__ bv, const float* __restrict__ bp,
    const float* __restrict__ as0, const float* __restrict__ ad0,
    const float* __restrict__ as1, const float* __restrict__ ad1,
    const short* __restrict__ wsb,
    float* __restrict__ out)
{
  // 2 items x 5120 shorts = 20480 B -> 8 blocks/CU (163840/20480 = 8), 32 waves/CU.
  // Per item: x[32 tok][XSTR] (shorts [0,4352)) aliases hT halves (hw*2560 + [0,2560)).
  // x and hT never coexist (frags register-staged around barriers).
  __shared__ __align__(16) short s_t[2][TILE];

  const int tid  = threadIdx.x;
  const int lane = tid & 63;
  const int wv   = tid >> 6;      // 0..3
  const int item = wv >> 1;       // 0..1
  const int hw   = wv & 1;        // half: heads {2hw,2hw+1}, e-rows [64hw,64hw+64), mt [4hw,4hw+4)
  const int col  = lane & 15;
  const int quad = lane >> 4;
  const int b    = blockIdx.x * 2 + item;

  const float* orow = obs + (size_t)b * OBSL;
  short* xbase = s_t[item];                     // x[tok][e], stride XSTR
  short* hbase = &s_t[item][hw * 2560];         // wave-private hT half: [64 e-loc][HSTR]
  const short8  z8 = {0,0,0,0,0,0,0,0};
  const floatx4 fz = {0.f,0.f,0.f,0.f};

  // ---------------- P0: alive flags (both waves redundantly), pad, scatter ----------------
  float flag; float invc;
  {
    float araw = (lane < NTOK) ? orow[1024 + lane] : 0.f;
    bool alv = (lane < NTOK) && (araw >= 0.5f);
    unsigned long long m = __ballot(alv);
    int cnt = __popcll(m);
    flag = alv ? 1.f : 0.f;
    if (cnt == 0) { flag = (lane < NTOK) ? 1.f : 0.f; cnt = NTOK; }
    invc = 1.f / (float)cnt;
  }
  const float alvI0 = __shfl(flag, col);        // alive of token col / 16+col (pool layout)
  const float alvI1 = __shfl(flag, 16 + col);

  #pragma unroll
  for (int it = 0; it < 2; ++it) {              // zero cols [0,64): wave hw pads rows 16hw..16hw+15
    int c = (hw * 2 + it) * 64 + lane;
    *(short8*)&xbase[(c >> 3) * XSTR + (c & 7) * 8] = z8;
  }
  __syncthreads();                              // pad done before scatter (row ranges overlap across waves)
  // 1024 data floats = 256 float4, split 128/wave; DV=40, DP=24 both %4==0
  #pragma unroll
  for (int it = 0; it < 2; ++it) {
    int i4 = (hw * 2 + it) * 64 + lane;
    float4 v = *(const float4*)&orow[i4 * 4];
    int r, k;
    if (i4 < 160) { r = (i4 * 205) >> 11;  k = (i4 - r * 10) * 4; }              // /10 magic (i4<160)
    else { int t2 = i4 - 160; int q6 = (t2 * 171) >> 10; r = 16 + q6; k = 40 + (t2 - q6 * 6) * 4; } // /6 magic (t2<96)
    uint2v u; u.x = pk2(v.x, v.y); u.y = pk2(v.z, v.w);
    *(uint2v*)&xbase[r * XSTR + k] = u;
  }
  __syncthreads();                              // scatter complete before Bxin reads

  // ---------------- P1: embed  D[e][tok] = embT x xin; wave computes e-rows [64hw,64hw+64) ----------------
  {
    short8 Bxin[2][2];                          // full K=64 of x_in
    #pragma unroll
    for (int nt = 0; nt < 2; ++nt)
      #pragma unroll
      for (int kt = 0; kt < 2; ++kt)
        Bxin[nt][kt] = *(const short8*)&xbase[(nt * 16 + col) * XSTR + kt * 32 + quad * 8];
    __syncthreads();                            // x_in reads done before embed overwrites cols
    const short* embT = wsb;
    #pragma unroll
    for (int mi = 0; mi < 4; ++mi) {
      const int mtE = hw * 4 + mi;
      short8 A0 = *(const short8*)&embT[(mtE * 16 + col) * 64 + quad * 8];
      short8 A1 = *(const short8*)&embT[(mtE * 16 + col) * 64 + 32 + quad * 8];
      float4 bv4 = *(const float4*)&bv[mtE * 16 + quad * 4];
      float4 bp4 = *(const float4*)&bp[mtE * 16 + quad * 4];
      #pragma unroll
      for (int nt = 0; nt < 2; ++nt) {
        floatx4 acc = fz;
        acc = mfma16(A0, Bxin[nt][0], acc);
        acc = mfma16(A1, Bxin[nt][1], acc);
        float4 bb = nt ? bp4 : bv4;
        uint2v u; u.x = pk2(acc[0] + bb.x, acc[1] + bb.y); u.y = pk2(acc[2] + bb.z, acc[3] + bb.w);
        *(uint2v*)&xbase[(nt * 16 + col) * XSTR + mtE * 16 + quad * 4] = u;
      }
    }
  }

  // ---------------- GAT layers ----------------
  for (int L = 0; L < 2; ++L) {
    const short* wT  = wsb + 8192 + L * 16384;
    const float* gas = L ? as1 : as0;
    const float* gad = L ? ad1 : ad0;

    __syncthreads();                            // x complete (embed / other wave's x_next) before reads

    short8 Bx[4][2];                            // full x as B-frags (K=128)
    #pragma unroll
    for (int kt = 0; kt < 4; ++kt)
      #pragma unroll
      for (int nt = 0; nt < 2; ++nt)
        Bx[kt][nt] = *(const short8*)&xbase[(nt * 16 + col) * XSTR + kt * 32 + quad * 8];
    __syncthreads();                            // bar#1: x reads done before hT writes (aliased)

    // hT-half[e_loc][tok] = wT x xT for this wave's 4 m-tiles, 2 groups of 2
    float psrc[2][2], pdst[2][2];
    #pragma unroll
    for (int hl = 0; hl < 2; ++hl) { psrc[hl][0]=0.f; psrc[hl][1]=0.f; pdst[hl][0]=0.f; pdst[hl][1]=0.f; }
    #pragma unroll
    for (int g = 0; g < 2; ++g) {               // group g = local head hl
      floatx4 acc[2][2];
      #pragma unroll
      for (int mi = 0; mi < 2; ++mi) { acc[mi][0] = fz; acc[mi][1] = fz; }
      #pragma unroll
      for (int mi = 0; mi < 2; ++mi) {
        const int mt = hw * 4 + g * 2 + mi;     // global m-tile
        const short* wrow = &wT[(mt * 16 + col) * 128 + quad * 8];
        short8 A0 = *(const short8*)&wrow[0];
        short8 A1 = *(const short8*)&wrow[32];
        short8 A2 = *(const short8*)&wrow[64];
        short8 A3 = *(const short8*)&wrow[96];
        #pragma unroll
        for (int nt = 0; nt < 2; ++nt) {
          acc[mi][nt] = mfma16(A0, Bx[0][nt], acc[mi][nt]);
          acc[mi][nt] = mfma16(A1, Bx[1][nt], acc[mi][nt]);
          acc[mi][nt] = mfma16(A2, Bx[2][nt], acc[mi][nt]);
          acc[mi][nt] = mfma16(A3, Bx[3][nt], acc[mi][nt]);
        }
      }
      #pragma unroll
      for (int mi = 0; mi < 2; ++mi) {
        const int mt = hw * 4 + g * 2 + mi;
        float4 cs = *(const float4*)&gas[mt * 16 + quad * 4];
        float4 cd = *(const float4*)&gad[mt * 16 + quad * 4];
        const int rowloc = (g * 2 + mi) * 16 + quad * 4;   // e-local row
        #pragma unroll
        for (int nt = 0; nt < 2; ++nt) {
          floatx4 a = acc[mi][nt];
          psrc[g][nt] += a[0]*cs.x + a[1]*cs.y + a[2]*cs.z + a[3]*cs.w;
          pdst[g][nt] += a[0]*cd.x + a[1]*cd.y + a[2]*cd.z + a[3]*cd.w;
          unsigned u01 = pk2(a[0], a[1]);
          unsigned u23 = pk2(a[2], a[3]);
          unsigned short* hrow = (unsigned short*)&hbase[rowloc * HSTR + nt * 16 + col];
          hrow[0]        = (unsigned short)u01;
          hrow[HSTR]     = (unsigned short)(u01 >> 16);
          hrow[2 * HSTR] = (unsigned short)u23;
          hrow[3 * HSTR] = (unsigned short)(u23 >> 16);
        }
      }
    }

    // full per-token alpha in every lane (token = nt*16 + col), scaled to exp2 domain
    #pragma unroll
    for (int hl = 0; hl < 2; ++hl)
      #pragma unroll
      for (int nt = 0; nt < 2; ++nt) {
        float vs = psrc[hl][nt]; vs += __shfl_xor(vs, 16); vs += __shfl_xor(vs, 32);
        psrc[hl][nt] = vs * 1.44269504088896340736f;
        float vd = pdst[hl][nt]; vd += __shfl_xor(vd, 16); vd += __shfl_xor(vd, 32);
        pdst[hl][nt] = vd * 1.44269504088896340736f;
      }

    float alv8[8];                              // alive of keys j = quad*8+jj (short liveness)
    #pragma unroll
    for (int jj = 0; jj < 8; ++jj) alv8[jj] = __shfl(flag, quad * 8 + jj);

    // softmax in PV B-frag layout: lane owns (i = ii*16+col, j = quad*8+jj)
    short8 pf[2][2];
    #pragma unroll
    for (int hl = 0; hl < 2; ++hl) {
      float vsel = (quad >> 1) ? pdst[hl][1] : pdst[hl][0];
      float ad8[8];
      #pragma unroll
      for (int jj = 0; jj < 8; ++jj) {
        float v = __shfl(vsel, ((quad >> 1) << 5) + ((quad & 1) << 3) + jj);
        ad8[jj] = (alv8[jj] >= 0.5f) ? v : -1e30f;   // dead keys -> exp2 -> 0
      }
      #pragma unroll
      for (int ii = 0; ii < 2; ++ii) {
        float ai = psrc[hl][ii];
        float ev[8]; float sum = 0.f;
        #pragma unroll
        for (int jj = 0; jj < 8; ++jj) {
          float e = ai + ad8[jj];
          e = fmaxf(e, 0.2f * e);                    // leaky-relu (commutes with log2e scale)
          float p = exp2_hw(e);
          ev[jj] = p; sum += p;
        }
        sum += __shfl_xor(sum, 16);
        sum += __shfl_xor(sum, 32);
        float inv = rcp_hw(sum);
        union { unsigned u4[4]; short8 s; } pu;
        #pragma unroll
        for (int p2 = 0; p2 < 4; ++p2) pu.u4[p2] = pk2(ev[2*p2] * inv, ev[2*p2+1] * inv);
        pf[hl][ii] = pu.s;
      }
    }

    // PV A-frags from own (wave-private) hT half; then barrier; then MFMA + epilogue
    short8 Ah[2][2];
    #pragma unroll
    for (int hl = 0; hl < 2; ++hl)
      #pragma unroll
      for (int mt2 = 0; mt2 < 2; ++mt2)
        Ah[hl][mt2] = *(const short8*)&hbase[(hl * 32 + mt2 * 16 + col) * HSTR + quad * 8];
    if (L == 0) __syncthreads();                // bar#2: hT reads done before x_next writes (aliased)

    #pragma unroll
    for (int hl = 0; hl < 2; ++hl)
      #pragma unroll
      for (int mt2 = 0; mt2 < 2; ++mt2) {
        floatx4 po[2];
        #pragma unroll
        for (int nt = 0; nt < 2; ++nt) {
          po[nt] = mfma16(Ah[hl][mt2], pf[hl][nt], fz);
        }
        const int ecol = hw * 64 + hl * 32 + mt2 * 16 + quad * 4;  // global e
        if (L == 0) {
          #pragma unroll
          for (int nt = 0; nt < 2; ++nt) {
            uint2v u;
            u.x = pk2(elu1(po[nt][0]), elu1(po[nt][1]));
            u.y = pk2(elu1(po[nt][2]), elu1(po[nt][3]));
            *(uint2v*)&xbase[(nt * 16 + col) * XSTR + ecol] = u;
          }
        } else {
          #pragma unroll
          for (int r = 0; r < 4; ++r) {
            float s = elu1(po[0][r]) * alvI0 + elu1(po[1][r]) * alvI1;
            s += __shfl_xor(s, 1); s += __shfl_xor(s, 2);
            s += __shfl_xor(s, 4); s += __shfl_xor(s, 8);
            if (col == 0) out[(size_t)b * EMB + ecol + r] = s * invc;  // direct store, 4 lanes
          }
        }
      }
  }
}

extern "C" void kernel_launch(void* const* d_in, const int* in_sizes, int n_in,
                              void* d_out, int out_size, void* d_ws, size_t ws_size,
                              hipStream_t stream) {
  const float* obs = (const float*)d_in[0];
  const float* Wv  = (const float*)d_in[1];
  const float* bv  = (const float*)d_in[2];
  const float* Wp  = (const float*)d_in[3];
  const float* bp  = (const float*)d_in[4];
  const float* w0  = (const float*)d_in[5];
  const float* as0 = (const float*)d_in[6];
  const float* ad0 = (const float*)d_in[7];
  const float* w1  = (const float*)d_in[8];
  const float* as1 = (const float*)d_in[9];
  const float* ad1 = (const float*)d_in[10];
  float* out = (float*)d_out;
  short* wsb = (short*)d_ws;                      // uses exactly 80 KiB

  int Bn = in_sizes[0] / OBSL;                    // 4096
  prep_weights<<<160, 256, 0, stream>>>(Wv, Wp, w0, w1, wsb);
  gnn_fused<<<Bn / 2, 256, 0, stream>>>(obs, bv, bp, as0, ad0, as1, ad1, wsb, out);
}

// Round 8
// 143.365 us; speedup vs baseline: 1.1200x; 1.1200x over previous
//
#include <hip/hip_runtime.h>

// GNNCriticEncoder fused kernel v10 == v9 resubmit (MI355X / gfx950)
// Round 7 gave no data: pytest core-dump on a degraded container (418s npz push;
// 3rd infra failure this session). v9 audit found no kernel-side fault candidate:
// all global/LDS accesses bounded, barriers uniform, no float/short LDS TBAA pairs.
// Resubmitting unchanged to get the datapoint.
// Design (from v6 diagnosis: latency-bound, all pipes idle, occupancy LDS-capped):
//  - 2 waves/item (head-split): each wave owns 2 heads / 64 e-rows / 4 m-tiles;
//    GEMM, alpha, softmax, PV, pool all wave-local. Aliased x<->hT tile, 20480 B/block
//    -> LDS permits 8 blocks/CU (2x v6 occupancy).
//  - launch_bounds(256,6): VGPR cap ~84 (v7's (256,8) cap-64 caused 172MB spill traffic).
//  - acc-major hT GEMM to fit under 84: B-frags re-read per K-tile (no 32-VGPR x stage);
//    bar#1 after the K-loop so all x reads still precede all (aliased) hT writes.
//  - epilogue: v7's proven direct global stores (v8's pool-in-LDS hit float/short TBAA
//    reordering -> corrupted PV operands).
// ws = exactly 81920 B (do not exceed).

#define NTOK 32
#define EMB  128
#define OBSL 1056
#define XSTR 136   // x row stride in shorts (272 B, 16B-aligned rows)
#define HSTR 40    // hT row stride in shorts (80 B: 16B-aligned)
#define TILE 5120  // shorts per item tile = max(x 32*136=4352, hT 2*64*40=5120)

typedef __attribute__((ext_vector_type(8))) short  short8;   // 8 x bf16 MFMA A/B frag
typedef __attribute__((ext_vector_type(4))) float  floatx4;  // MFMA C/D frag
typedef __attribute__((ext_vector_type(2))) unsigned uint2v;

__device__ __forceinline__ short f2bf(float f) {             // scalar RNE (prep kernel only)
  union { float f; unsigned u; } v; v.f = f;
  unsigned r = (v.u + 0x7fffu + ((v.u >> 16) & 1u)) >> 16;
  return (short)(unsigned short)r;
}
// HW packed fp32->bf16 (RNE): plain VALU op, safe in inline asm
__device__ __forceinline__ unsigned pk2(float a, float b) {
  unsigned r; asm("v_cvt_pk_bf16_f32 %0, %1, %2" : "=v"(r) : "v"(a), "v"(b)); return r;
}
__device__ __forceinline__ float exp2_hw(float x) {
#if __has_builtin(__builtin_amdgcn_exp2f)
  return __builtin_amdgcn_exp2f(x);
#else
  return exp2f(x);
#endif
}
__device__ __forceinline__ float rcp_hw(float x) {
#if __has_builtin(__builtin_amdgcn_rcpf)
  return __builtin_amdgcn_rcpf(x);
#else
  return 1.0f / x;
#endif
}
__device__ __forceinline__ float elu1(float v) { return v > 0.f ? v : __expf(v) - 1.f; }
__device__ __forceinline__ floatx4 mfma16(short8 a, short8 b, floatx4 c) {
  return __builtin_amdgcn_mfma_f32_16x16x32_bf16(a, b, c, 0, 0, 0);
}

// ws layout (bf16): [0,8192) embT[e][k] (k<40 Wv, else Wp) | [8192,24576) wT0[e][k] | [24576,40960) wT1[e][k]
// Total: 40960 shorts = exactly 81920 B. DO NOT EXCEED (ws_size appears to be 80 KiB).
__global__ void prep_weights(const float* __restrict__ Wv, const float* __restrict__ Wp,
                             const float* __restrict__ w0, const float* __restrict__ w1,
                             short* __restrict__ ws) {
  int idx = blockIdx.x * 256 + threadIdx.x;          // 160 blocks x 256 = 40960
  if (idx < 8192) {
    int e = idx >> 6, k = idx & 63;
    float v = (k < 40) ? Wv[(size_t)k * EMB + e] : Wp[(size_t)(k - 40) * EMB + e];
    ws[idx] = f2bf(v);
  } else if (idx < 24576) {
    int t = idx - 8192; int e = t >> 7, k = t & 127;
    ws[idx] = f2bf(w0[(size_t)k * EMB + e]);
  } else {
    int t = idx - 24576; int e = t >> 7, k = t & 127;
    ws[idx] = f2bf(w1[(size_t)k * EMB + e]);
  }
}

__global__ __launch_bounds__(256, 6) void gnn_fused(
    const float* __restrict__ obs,
    const float* __restrict__ bv, const float* __restrict__ bp,
    const float* __restrict__ as0, const float* __restrict__ ad0,
    const float* __restrict__ as1, const float* __restrict__ ad1,
    const short* __restrict__ wsb,
    float* __restrict__ out)
{
  // 2 items x 5120 shorts = 20480 B. Per item: x[32 tok][XSTR] (shorts [0,4352))
  // aliases hT halves (hw*2560 + [0,2560)); x and hT never coexist.
  __shared__ __align__(16) short s_t[2][TILE];

  const int tid  = threadIdx.x;
  const int lane = tid & 63;
  const int wv   = tid >> 6;      // 0..3
  const int item = wv >> 1;       // 0..1
  const int hw   = wv & 1;        // half: heads {2hw,2hw+1}, e-rows [64hw,64hw+64), mt [4hw,4hw+4)
  const int col  = lane & 15;
  const int quad = lane >> 4;
  const int b    = blockIdx.x * 2 + item;

  const float* orow = obs + (size_t)b * OBSL;
  short* xbase = s_t[item];                     // x[tok][e], stride XSTR
  short* hbase = &s_t[item][hw * 2560];         // wave-private hT half: [64 e-loc][HSTR]
  const short8  z8 = {0,0,0,0,0,0,0,0};
  const floatx4 fz = {0.f,0.f,0.f,0.f};

  // ---------------- P0: alive flags (both waves redundantly), pad, scatter ----------------
  float flag; float invc;
  {
    float araw = (lane < NTOK) ? orow[1024 + lane] : 0.f;
    bool alv = (lane < NTOK) && (araw >= 0.5f);
    unsigned long long m = __ballot(alv);
    int cnt = __popcll(m);
    flag = alv ? 1.f : 0.f;
    if (cnt == 0) { flag = (lane < NTOK) ? 1.f : 0.f; cnt = NTOK; }
    invc = 1.f / (float)cnt;
  }
  const float alvI0 = __shfl(flag, col);        // alive of token col / 16+col (pool layout)
  const float alvI1 = __shfl(flag, 16 + col);

  #pragma unroll
  for (int it = 0; it < 2; ++it) {              // zero cols [0,64): wave hw pads rows 16hw..16hw+15
    int c = (hw * 2 + it) * 64 + lane;
    *(short8*)&xbase[(c >> 3) * XSTR + (c & 7) * 8] = z8;
  }
  __syncthreads();                              // pad done before scatter (row ranges overlap across waves)
  // 1024 data floats = 256 float4, split 128/wave; DV=40, DP=24 both %4==0
  #pragma unroll
  for (int it = 0; it < 2; ++it) {
    int i4 = (hw * 2 + it) * 64 + lane;
    float4 v = *(const float4*)&orow[i4 * 4];
    int r, k;
    if (i4 < 160) { r = (i4 * 205) >> 11;  k = (i4 - r * 10) * 4; }              // /10 magic (i4<160)
    else { int t2 = i4 - 160; int q6 = (t2 * 171) >> 10; r = 16 + q6; k = 40 + (t2 - q6 * 6) * 4; } // /6 magic (t2<96)
    uint2v u; u.x = pk2(v.x, v.y); u.y = pk2(v.z, v.w);
    *(uint2v*)&xbase[r * XSTR + k] = u;
  }
  __syncthreads();                              // scatter complete before Bxin reads

  // ---------------- P1: embed  D[e][tok] = embT x xin; wave computes e-rows [64hw,64hw+64) ----------------
  {
    short8 Bxin[2][2];                          // full K=64 of x_in
    #pragma unroll
    for (int nt = 0; nt < 2; ++nt)
      #pragma unroll
      for (int kt = 0; kt < 2; ++kt)
        Bxin[nt][kt] = *(const short8*)&xbase[(nt * 16 + col) * XSTR + kt * 32 + quad * 8];
    __syncthreads();                            // x_in reads done before embed overwrites cols
    const short* embT = wsb;
    #pragma unroll
    for (int mi = 0; mi < 4; ++mi) {
      const int mtE = hw * 4 + mi;
      short8 A0 = *(const short8*)&embT[(mtE * 16 + col) * 64 + quad * 8];
      short8 A1 = *(const short8*)&embT[(mtE * 16 + col) * 64 + 32 + quad * 8];
      float4 bv4 = *(const float4*)&bv[mtE * 16 + quad * 4];
      float4 bp4 = *(const float4*)&bp[mtE * 16 + quad * 4];
      #pragma unroll
      for (int nt = 0; nt < 2; ++nt) {
        floatx4 acc = fz;
        acc = mfma16(A0, Bxin[nt][0], acc);
        acc = mfma16(A1, Bxin[nt][1], acc);
        float4 bb = nt ? bp4 : bv4;
        uint2v u; u.x = pk2(acc[0] + bb.x, acc[1] + bb.y); u.y = pk2(acc[2] + bb.z, acc[3] + bb.w);
        *(uint2v*)&xbase[(nt * 16 + col) * XSTR + mtE * 16 + quad * 4] = u;
      }
    }
  }

  // ---------------- GAT layers ----------------
  for (int L = 0; L < 2; ++L) {
    const short* wT  = wsb + 8192 + L * 16384;
    const float* gas = L ? as1 : as0;
    const float* gad = L ? ad1 : ad0;

    __syncthreads();                            // x complete (embed / other wave's x_next) before reads

    // hT GEMM, acc-major: all 4 m-tiles accumulate across K; B-frags re-read per K-tile
    // (peak live = acc 32 + B 8 + A transient, vs 32 staged Bx in v7/v8).
    floatx4 acc[4][2];
    #pragma unroll
    for (int mi = 0; mi < 4; ++mi) { acc[mi][0] = fz; acc[mi][1] = fz; }
    #pragma unroll
    for (int kt = 0; kt < 4; ++kt) {
      short8 B0 = *(const short8*)&xbase[(col) * XSTR + kt * 32 + quad * 8];
      short8 B1 = *(const short8*)&xbase[(16 + col) * XSTR + kt * 32 + quad * 8];
      #pragma unroll
      for (int mi = 0; mi < 4; ++mi) {
        const int mt = hw * 4 + mi;
        short8 A = *(const short8*)&wT[(mt * 16 + col) * 128 + kt * 32 + quad * 8];
        acc[mi][0] = mfma16(A, B0, acc[mi][0]);
        acc[mi][1] = mfma16(A, B1, acc[mi][1]);
      }
    }

    // alpha partials from accs (VALU work before the barrier)
    float psrc[2][2], pdst[2][2];
    #pragma unroll
    for (int hl = 0; hl < 2; ++hl) { psrc[hl][0]=0.f; psrc[hl][1]=0.f; pdst[hl][0]=0.f; pdst[hl][1]=0.f; }
    #pragma unroll
    for (int mi = 0; mi < 4; ++mi) {
      const int mt = hw * 4 + mi;
      const int hl = mi >> 1;
      float4 cs = *(const float4*)&gas[mt * 16 + quad * 4];
      float4 cd = *(const float4*)&gad[mt * 16 + quad * 4];
      #pragma unroll
      for (int nt = 0; nt < 2; ++nt) {
        floatx4 a = acc[mi][nt];
        psrc[hl][nt] += a[0]*cs.x + a[1]*cs.y + a[2]*cs.z + a[3]*cs.w;
        pdst[hl][nt] += a[0]*cd.x + a[1]*cd.y + a[2]*cd.z + a[3]*cd.w;
      }
    }
    __syncthreads();                            // bar#1: ALL waves' x reads done before hT writes (aliased)

    // hT writes from accs (ushort stores alias short reads -> program order preserved)
    #pragma unroll
    for (int mi = 0; mi < 4; ++mi) {
      const int rowloc = mi * 16 + quad * 4;    // e-local row
      #pragma unroll
      for (int nt = 0; nt < 2; ++nt) {
        floatx4 a = acc[mi][nt];
        unsigned u01 = pk2(a[0], a[1]);
        unsigned u23 = pk2(a[2], a[3]);
        unsigned short* hrow = (unsigned short*)&hbase[rowloc * HSTR + nt * 16 + col];
        hrow[0]        = (unsigned short)u01;
        hrow[HSTR]     = (unsigned short)(u01 >> 16);
        hrow[2 * HSTR] = (unsigned short)u23;
        hrow[3 * HSTR] = (unsigned short)(u23 >> 16);
      }
    }

    // full per-token alpha in every lane (token = nt*16 + col), scaled to exp2 domain
    #pragma unroll
    for (int hl = 0; hl < 2; ++hl)
      #pragma unroll
      for (int nt = 0; nt < 2; ++nt) {
        float vs = psrc[hl][nt]; vs += __shfl_xor(vs, 16); vs += __shfl_xor(vs, 32);
        psrc[hl][nt] = vs * 1.44269504088896340736f;
        float vd = pdst[hl][nt]; vd += __shfl_xor(vd, 16); vd += __shfl_xor(vd, 32);
        pdst[hl][nt] = vd * 1.44269504088896340736f;
      }

    float alv8[8];                              // alive of keys j = quad*8+jj (short liveness)
    #pragma unroll
    for (int jj = 0; jj < 8; ++jj) alv8[jj] = __shfl(flag, quad * 8 + jj);

    // softmax in PV B-frag layout: lane owns (i = ii*16+col, j = quad*8+jj)
    short8 pf[2][2];
    #pragma unroll
    for (int hl = 0; hl < 2; ++hl) {
      float vsel = (quad >> 1) ? pdst[hl][1] : pdst[hl][0];
      float ad8[8];
      #pragma unroll
      for (int jj = 0; jj < 8; ++jj) {
        float v = __shfl(vsel, ((quad >> 1) << 5) + ((quad & 1) << 3) + jj);
        ad8[jj] = (alv8[jj] >= 0.5f) ? v : -1e30f;   // dead keys -> exp2 -> 0
      }
      #pragma unroll
      for (int ii = 0; ii < 2; ++ii) {
        float ai = psrc[hl][ii];
        float ev[8]; float sum = 0.f;
        #pragma unroll
        for (int jj = 0; jj < 8; ++jj) {
          float e = ai + ad8[jj];
          e = fmaxf(e, 0.2f * e);                    // leaky-relu (commutes with log2e scale)
          float p = exp2_hw(e);
          ev[jj] = p; sum += p;
        }
        sum += __shfl_xor(sum, 16);
        sum += __shfl_xor(sum, 32);
        float inv = rcp_hw(sum);
        union { unsigned u4[4]; short8 s; } pu;
        #pragma unroll
        for (int p2 = 0; p2 < 4; ++p2) pu.u4[p2] = pk2(ev[2*p2] * inv, ev[2*p2+1] * inv);
        pf[hl][ii] = pu.s;
      }
    }

    // PV A-frags from own (wave-private) hT half; then barrier; then MFMA + epilogue
    short8 Ah[2][2];
    #pragma unroll
    for (int hl = 0; hl < 2; ++hl)
      #pragma unroll
      for (int mt2 = 0; mt2 < 2; ++mt2)
        Ah[hl][mt2] = *(const short8*)&hbase[(hl * 32 + mt2 * 16 + col) * HSTR + quad * 8];
    if (L == 0) __syncthreads();                // bar#2: hT reads done before x_next writes (aliased)

    #pragma unroll
    for (int hl = 0; hl < 2; ++hl)
      #pragma unroll
      for (int mt2 = 0; mt2 < 2; ++mt2) {
        floatx4 po[2];
        #pragma unroll
        for (int nt = 0; nt < 2; ++nt) {
          po[nt] = mfma16(Ah[hl][mt2], pf[hl][nt], fz);
        }
        const int ecol = hw * 64 + hl * 32 + mt2 * 16 + quad * 4;  // global e
        if (L == 0) {
          #pragma unroll
          for (int nt = 0; nt < 2; ++nt) {
            uint2v u;
            u.x = pk2(elu1(po[nt][0]), elu1(po[nt][1]));
            u.y = pk2(elu1(po[nt][2]), elu1(po[nt][3]));
            *(uint2v*)&xbase[(nt * 16 + col) * XSTR + ecol] = u;
          }
        } else {
          #pragma unroll
          for (int r = 0; r < 4; ++r) {
            float s = elu1(po[0][r]) * alvI0 + elu1(po[1][r]) * alvI1;
            s += __shfl_xor(s, 1); s += __shfl_xor(s, 2);
            s += __shfl_xor(s, 4); s += __shfl_xor(s, 8);
            if (col == 0) out[(size_t)b * EMB + ecol + r] = s * invc;  // direct store (proven v7 path)
          }
        }
      }
  }
}

extern "C" void kernel_launch(void* const* d_in, const int* in_sizes, int n_in,
                              void* d_out, int out_size, void* d_ws, size_t ws_size,
                              hipStream_t stream) {
  const float* obs = (const float*)d_in[0];
  const float* Wv  = (const float*)d_in[1];
  const float* bv  = (const float*)d_in[2];
  const float* Wp  = (const float*)d_in[3];
  const float* bp  = (const float*)d_in[4];
  const float* w0  = (const float*)d_in[5];
  const float* as0 = (const float*)d_in[6];
  const float* ad0 = (const float*)d_in[7];
  const float* w1  = (const float*)d_in[8];
  const float* as1 = (const float*)d_in[9];
  const float* ad1 = (const float*)d_in[10];
  float* out = (float*)d_out;
  short* wsb = (short*)d_ws;                      // uses exactly 80 KiB

  int Bn = in_sizes[0] / OBSL;                    // 4096
  prep_weights<<<160, 256, 0, stream>>>(Wv, Wp, w0, w1, wsb);
  gnn_fused<<<Bn / 2, 256, 0, stream>>>(obs, bv, bp, as0, ad0, as1, ad1, wsb, out);
}

// Round 9
// 130.247 us; speedup vs baseline: 1.2328x; 1.1007x over previous
//
#include <hip/hip_runtime.h>

// GNNCriticEncoder fused kernel v11 (MI355X / gfx950)
// v10 post-mortem: passed, 71.5us, but occupancy only 47% (~4 blocks/CU) -> true
// register footprint (VGPR 40 arch + AGPR accs, unified file) ~100-128/thread caps
// waves/SIMD at 4. Still latency-bound (MFMA 6.9%, VALU 31%).
// v11: FOUR waves per item -- wave wv owns head wv (2 m-tiles, 32 e-rows, own
// alpha/softmax/PV/pool). Per-wave state: acc[2][2]=16 + B 16 + A 8 ~= 55 regs total
// -> 8 waves/SIMD feasible. LDS 10240 B/block (x 8704 B aliasing 4 wave-private hT
// quarters of 2560 B); blocks/CU capped by wave count at 8 -> 80KB LDS, 100% occ
// theoretical. Barriers now sync 1 item (4 waves), not 2.
// Same arithmetic/orders per head as v10 -> bitwise-same output expected.
// ws = exactly 81920 B (do not exceed).

#define NTOK 32
#define EMB  128
#define OBSL 1056
#define XSTR 136   // x row stride in shorts (272 B, 16B-aligned rows)
#define HSTR 40    // hT row stride in shorts (80 B: 16B-aligned)
#define TILE 5120  // shorts per item tile = max(x 32*136=4352, hT 4*32*40=5120)

typedef __attribute__((ext_vector_type(8))) short  short8;   // 8 x bf16 MFMA A/B frag
typedef __attribute__((ext_vector_type(4))) float  floatx4;  // MFMA C/D frag
typedef __attribute__((ext_vector_type(2))) unsigned uint2v;

__device__ __forceinline__ short f2bf(float f) {             // scalar RNE (prep kernel only)
  union { float f; unsigned u; } v; v.f = f;
  unsigned r = (v.u + 0x7fffu + ((v.u >> 16) & 1u)) >> 16;
  return (short)(unsigned short)r;
}
// HW packed fp32->bf16 (RNE): plain VALU op, safe in inline asm
__device__ __forceinline__ unsigned pk2(float a, float b) {
  unsigned r; asm("v_cvt_pk_bf16_f32 %0, %1, %2" : "=v"(r) : "v"(a), "v"(b)); return r;
}
__device__ __forceinline__ float exp2_hw(float x) {
#if __has_builtin(__builtin_amdgcn_exp2f)
  return __builtin_amdgcn_exp2f(x);
#else
  return exp2f(x);
#endif
}
__device__ __forceinline__ float rcp_hw(float x) {
#if __has_builtin(__builtin_amdgcn_rcpf)
  return __builtin_amdgcn_rcpf(x);
#else
  return 1.0f / x;
#endif
}
__device__ __forceinline__ float elu1(float v) { return v > 0.f ? v : __expf(v) - 1.f; }
__device__ __forceinline__ floatx4 mfma16(short8 a, short8 b, floatx4 c) {
  return __builtin_amdgcn_mfma_f32_16x16x32_bf16(a, b, c, 0, 0, 0);
}

// ws layout (bf16): [0,8192) embT[e][k] (k<40 Wv, else Wp) | [8192,24576) wT0[e][k] | [24576,40960) wT1[e][k]
// Total: 40960 shorts = exactly 81920 B. DO NOT EXCEED (ws_size appears to be 80 KiB).
__global__ void prep_weights(const float* __restrict__ Wv, const float* __restrict__ Wp,
                             const float* __restrict__ w0, const float* __restrict__ w1,
                             short* __restrict__ ws) {
  int idx = blockIdx.x * 256 + threadIdx.x;          // 160 blocks x 256 = 40960
  if (idx < 8192) {
    int e = idx >> 6, k = idx & 63;
    float v = (k < 40) ? Wv[(size_t)k * EMB + e] : Wp[(size_t)(k - 40) * EMB + e];
    ws[idx] = f2bf(v);
  } else if (idx < 24576) {
    int t = idx - 8192; int e = t >> 7, k = t & 127;
    ws[idx] = f2bf(w0[(size_t)k * EMB + e]);
  } else {
    int t = idx - 24576; int e = t >> 7, k = t & 127;
    ws[idx] = f2bf(w1[(size_t)k * EMB + e]);
  }
}

__global__ __launch_bounds__(256, 6) void gnn_fused(
    const float* __restrict__ obs,
    const float* __restrict__ bv, const float* __restrict__ bp,
    const float* __restrict__ as0, const float* __restrict__ ad0,
    const float* __restrict__ as1, const float* __restrict__ ad1,
    const short* __restrict__ wsb,
    float* __restrict__ out)
{
  // One item per block. x[32 tok][XSTR] (shorts [0,4352)) aliases 4 hT quarters
  // (wv*1280 + [0,1280)); x and hT never coexist (barrier-fenced).
  __shared__ __align__(16) short s_t[TILE];

  const int tid  = threadIdx.x;
  const int lane = tid & 63;
  const int wv   = tid >> 6;      // 0..3 = head; e-rows [32wv,32wv+32); m-tiles {2wv,2wv+1}
  const int col  = lane & 15;
  const int quad = lane >> 4;
  const int b    = blockIdx.x;

  const float* orow = obs + (size_t)b * OBSL;
  short* xbase = s_t;                           // x[tok][e], stride XSTR
  short* hbase = &s_t[wv * 1280];               // wave-private hT quarter: [32 e-loc][HSTR]
  const short8  z8 = {0,0,0,0,0,0,0,0};
  const floatx4 fz = {0.f,0.f,0.f,0.f};

  // ---------------- P0: alive flags (all 4 waves redundantly), pad, scatter ----------------
  float flag; float invc;
  {
    float araw = (lane < NTOK) ? orow[1024 + lane] : 0.f;
    bool alv = (lane < NTOK) && (araw >= 0.5f);
    unsigned long long m = __ballot(alv);
    int cnt = __popcll(m);
    flag = alv ? 1.f : 0.f;
    if (cnt == 0) { flag = (lane < NTOK) ? 1.f : 0.f; cnt = NTOK; }
    invc = 1.f / (float)cnt;
  }
  const float alvI0 = __shfl(flag, col);        // alive of token col / 16+col (pool layout)
  const float alvI1 = __shfl(flag, 16 + col);

  {                                             // zero cols [0,64) of all 32 rows, split 4 ways
    int c = wv * 64 + lane;                     // [0,256)
    *(short8*)&xbase[(c >> 3) * XSTR + (c & 7) * 8] = z8;
  }
  __syncthreads();                              // pad done before scatter (row ranges overlap across waves)
  {                                             // 1024 data floats = 256 float4, split 4 ways
    int i4 = wv * 64 + lane;                    // [0,256)
    float4 v = *(const float4*)&orow[i4 * 4];
    int r, k;
    if (i4 < 160) { r = (i4 * 205) >> 11;  k = (i4 - r * 10) * 4; }              // /10 magic (i4<160)
    else { int t2 = i4 - 160; int q6 = (t2 * 171) >> 10; r = 16 + q6; k = 40 + (t2 - q6 * 6) * 4; } // /6 magic (t2<96)
    uint2v u; u.x = pk2(v.x, v.y); u.y = pk2(v.z, v.w);
    *(uint2v*)&xbase[r * XSTR + k] = u;
  }
  __syncthreads();                              // scatter complete before Bxin reads

  // ---------------- P1: embed  D[e][tok] = embT x xin; wave computes e-rows [32wv,32wv+32) ----------------
  {
    short8 Bxin[2][2];                          // full K=64 of x_in
    #pragma unroll
    for (int nt = 0; nt < 2; ++nt)
      #pragma unroll
      for (int kt = 0; kt < 2; ++kt)
        Bxin[nt][kt] = *(const short8*)&xbase[(nt * 16 + col) * XSTR + kt * 32 + quad * 8];
    __syncthreads();                            // x_in reads done before embed overwrites cols
    const short* embT = wsb;
    #pragma unroll
    for (int mi = 0; mi < 2; ++mi) {
      const int mtE = wv * 2 + mi;
      short8 A0 = *(const short8*)&embT[(mtE * 16 + col) * 64 + quad * 8];
      short8 A1 = *(const short8*)&embT[(mtE * 16 + col) * 64 + 32 + quad * 8];
      float4 bv4 = *(const float4*)&bv[mtE * 16 + quad * 4];
      float4 bp4 = *(const float4*)&bp[mtE * 16 + quad * 4];
      #pragma unroll
      for (int nt = 0; nt < 2; ++nt) {
        floatx4 acc = fz;
        acc = mfma16(A0, Bxin[nt][0], acc);
        acc = mfma16(A1, Bxin[nt][1], acc);
        float4 bb = nt ? bp4 : bv4;
        uint2v u; u.x = pk2(acc[0] + bb.x, acc[1] + bb.y); u.y = pk2(acc[2] + bb.z, acc[3] + bb.w);
        *(uint2v*)&xbase[(nt * 16 + col) * XSTR + mtE * 16 + quad * 4] = u;
      }
    }
  }

  // ---------------- GAT layers ----------------
  for (int L = 0; L < 2; ++L) {
    const short* wT  = wsb + 8192 + L * 16384;
    const float* gas = L ? as1 : as0;
    const float* gad = L ? ad1 : ad0;

    __syncthreads();                            // x complete (embed / x_next) before reads

    // hT GEMM, acc-major: 2 m-tiles (own head) accumulate across K; B-frags re-read per K-tile
    floatx4 acc[2][2];
    #pragma unroll
    for (int mi = 0; mi < 2; ++mi) { acc[mi][0] = fz; acc[mi][1] = fz; }
    #pragma unroll
    for (int kt = 0; kt < 4; ++kt) {
      short8 B0 = *(const short8*)&xbase[(col) * XSTR + kt * 32 + quad * 8];
      short8 B1 = *(const short8*)&xbase[(16 + col) * XSTR + kt * 32 + quad * 8];
      #pragma unroll
      for (int mi = 0; mi < 2; ++mi) {
        const int mt = wv * 2 + mi;
        short8 A = *(const short8*)&wT[(mt * 16 + col) * 128 + kt * 32 + quad * 8];
        acc[mi][0] = mfma16(A, B0, acc[mi][0]);
        acc[mi][1] = mfma16(A, B1, acc[mi][1]);
      }
    }

    // alpha partials from accs (own head; VALU work before the barrier)
    float psrc[2], pdst[2];
    psrc[0] = 0.f; psrc[1] = 0.f; pdst[0] = 0.f; pdst[1] = 0.f;
    #pragma unroll
    for (int mi = 0; mi < 2; ++mi) {
      const int mt = wv * 2 + mi;
      float4 cs = *(const float4*)&gas[mt * 16 + quad * 4];
      float4 cd = *(const float4*)&gad[mt * 16 + quad * 4];
      #pragma unroll
      for (int nt = 0; nt < 2; ++nt) {
        floatx4 a = acc[mi][nt];
        psrc[nt] += a[0]*cs.x + a[1]*cs.y + a[2]*cs.z + a[3]*cs.w;
        pdst[nt] += a[0]*cd.x + a[1]*cd.y + a[2]*cd.z + a[3]*cd.w;
      }
    }
    __syncthreads();                            // bar#1: ALL waves' x reads done before hT writes (aliased)

    // hT writes from accs into own quarter (ushort stores alias short reads -> ordered)
    #pragma unroll
    for (int mi = 0; mi < 2; ++mi) {
      const int rowloc = mi * 16 + quad * 4;    // e-local row within quarter
      #pragma unroll
      for (int nt = 0; nt < 2; ++nt) {
        floatx4 a = acc[mi][nt];
        unsigned u01 = pk2(a[0], a[1]);
        unsigned u23 = pk2(a[2], a[3]);
        unsigned short* hrow = (unsigned short*)&hbase[rowloc * HSTR + nt * 16 + col];
        hrow[0]        = (unsigned short)u01;
        hrow[HSTR]     = (unsigned short)(u01 >> 16);
        hrow[2 * HSTR] = (unsigned short)u23;
        hrow[3 * HSTR] = (unsigned short)(u23 >> 16);
      }
    }

    // full per-token alpha in every lane (token = nt*16 + col), scaled to exp2 domain
    #pragma unroll
    for (int nt = 0; nt < 2; ++nt) {
      float vs = psrc[nt]; vs += __shfl_xor(vs, 16); vs += __shfl_xor(vs, 32);
      psrc[nt] = vs * 1.44269504088896340736f;
      float vd = pdst[nt]; vd += __shfl_xor(vd, 16); vd += __shfl_xor(vd, 32);
      pdst[nt] = vd * 1.44269504088896340736f;
    }

    float alv8[8];                              // alive of keys j = quad*8+jj (short liveness)
    #pragma unroll
    for (int jj = 0; jj < 8; ++jj) alv8[jj] = __shfl(flag, quad * 8 + jj);

    // softmax (own head) in PV B-frag layout: lane owns (i = ii*16+col, j = quad*8+jj)
    short8 pf[2];
    {
      float vsel = (quad >> 1) ? pdst[1] : pdst[0];
      float ad8[8];
      #pragma unroll
      for (int jj = 0; jj < 8; ++jj) {
        float v = __shfl(vsel, ((quad >> 1) << 5) + ((quad & 1) << 3) + jj);
        ad8[jj] = (alv8[jj] >= 0.5f) ? v : -1e30f;   // dead keys -> exp2 -> 0
      }
      #pragma unroll
      for (int ii = 0; ii < 2; ++ii) {
        float ai = psrc[ii];
        float ev[8]; float sum = 0.f;
        #pragma unroll
        for (int jj = 0; jj < 8; ++jj) {
          float e = ai + ad8[jj];
          e = fmaxf(e, 0.2f * e);                    // leaky-relu (commutes with log2e scale)
          float p = exp2_hw(e);
          ev[jj] = p; sum += p;
        }
        sum += __shfl_xor(sum, 16);
        sum += __shfl_xor(sum, 32);
        float inv = rcp_hw(sum);
        union { unsigned u4[4]; short8 s; } pu;
        #pragma unroll
        for (int p2 = 0; p2 < 4; ++p2) pu.u4[p2] = pk2(ev[2*p2] * inv, ev[2*p2+1] * inv);
        pf[ii] = pu.s;
      }
    }

    // PV A-frags from own (wave-private) hT quarter; then barrier; then MFMA + epilogue
    short8 Ah[2];
    #pragma unroll
    for (int mt2 = 0; mt2 < 2; ++mt2)
      Ah[mt2] = *(const short8*)&hbase[(mt2 * 16 + col) * HSTR + quad * 8];
    if (L == 0) __syncthreads();                // bar#2: hT reads done before x_next writes (aliased)

    #pragma unroll
    for (int mt2 = 0; mt2 < 2; ++mt2) {
      floatx4 po[2];
      #pragma unroll
      for (int nt = 0; nt < 2; ++nt) {
        po[nt] = mfma16(Ah[mt2], pf[nt], fz);
      }
      const int ecol = wv * 32 + mt2 * 16 + quad * 4;  // global e
      if (L == 0) {
        #pragma unroll
        for (int nt = 0; nt < 2; ++nt) {
          uint2v u;
          u.x = pk2(elu1(po[nt][0]), elu1(po[nt][1]));
          u.y = pk2(elu1(po[nt][2]), elu1(po[nt][3]));
          *(uint2v*)&xbase[(nt * 16 + col) * XSTR + ecol] = u;
        }
      } else {
        #pragma unroll
        for (int r = 0; r < 4; ++r) {
          float s = elu1(po[0][r]) * alvI0 + elu1(po[1][r]) * alvI1;
          s += __shfl_xor(s, 1); s += __shfl_xor(s, 2);
          s += __shfl_xor(s, 4); s += __shfl_xor(s, 8);
          if (col == 0) out[(size_t)b * EMB + ecol + r] = s * invc;  // direct store (proven path)
        }
      }
    }
  }
}

extern "C" void kernel_launch(void* const* d_in, const int* in_sizes, int n_in,
                              void* d_out, int out_size, void* d_ws, size_t ws_size,
                              hipStream_t stream) {
  const float* obs = (const float*)d_in[0];
  const float* Wv  = (const float*)d_in[1];
  const float* bv  = (const float*)d_in[2];
  const float* Wp  = (const float*)d_in[3];
  const float* bp  = (const float*)d_in[4];
  const float* w0  = (const float*)d_in[5];
  const float* as0 = (const float*)d_in[6];
  const float* ad0 = (const float*)d_in[7];
  const float* w1  = (const float*)d_in[8];
  const float* as1 = (const float*)d_in[9];
  const float* ad1 = (const float*)d_in[10];
  float* out = (float*)d_out;
  short* wsb = (short*)d_ws;                      // uses exactly 80 KiB

  int Bn = in_sizes[0] / OBSL;                    // 4096
  prep_weights<<<160, 256, 0, stream>>>(Wv, Wp, w0, w1, wsb);
  gnn_fused<<<Bn, 256, 0, stream>>>(obs, bv, bp, as0, ad0, as1, ad1, wsb, out);
}

// Round 10
// 128.812 us; speedup vs baseline: 1.2466x; 1.0111x over previous
//
#include <hip/hip_runtime.h>

// GNNCriticEncoder fused kernel v12 (MI355X / gfx950)
// v11 post-mortem: time tracks 1/resident-waves (v6 78.7@16w, v11 57.4@23w); per-wave
// VALU duty ~7% in both -> stall = barrier lockstep (8/item) + generation turnover
// (4096 blocks vs 2048 slots, occ 72.5%).
// v12: TWO items per wave (same head-split). Block = 4 waves = heads x items{2b,2b+1}.
//  - 7 barriers per 2 items (3.5/item): complement-pad makes pad/scatter disjoint
//    (no barrier), alive flags kept as wave-uniform ballot mask in SGPR (no shuffles).
//  - grid 2048 = exactly 8 blocks/CU x 256 CU -> single generation, no turnover.
//  - LDS 20480 B/block -> LDS cap exactly 8 blocks; regs kept ~<=60 at peak
//    (acc[j][mi][nt] 32 + per-j B 8 + A 4; A re-read per j -> VMEM, the idle pipe).
//  - weight frags / coeff loads amortized over 2 items; per-item math identical to v11.
// ws = exactly 81920 B (do not exceed).

#define NTOK 32
#define EMB  128
#define OBSL 1056
#define XSTR 136   // x row stride in shorts (272 B, 16B-aligned rows)
#define HSTR 40    // hT row stride in shorts (80 B: 16B-aligned)
#define TILE 5120  // shorts per item tile = max(x 32*136=4352, hT 4*32*40=5120)

typedef __attribute__((ext_vector_type(8))) short  short8;   // 8 x bf16 MFMA A/B frag (4 VGPR)
typedef __attribute__((ext_vector_type(4))) float  floatx4;  // MFMA C/D frag (4 VGPR)
typedef __attribute__((ext_vector_type(2))) unsigned uint2v;

__device__ __forceinline__ short f2bf(float f) {             // scalar RNE (prep kernel only)
  union { float f; unsigned u; } v; v.f = f;
  unsigned r = (v.u + 0x7fffu + ((v.u >> 16) & 1u)) >> 16;
  return (short)(unsigned short)r;
}
// HW packed fp32->bf16 (RNE): plain VALU op, safe in inline asm
__device__ __forceinline__ unsigned pk2(float a, float b) {
  unsigned r; asm("v_cvt_pk_bf16_f32 %0, %1, %2" : "=v"(r) : "v"(a), "v"(b)); return r;
}
__device__ __forceinline__ float exp2_hw(float x) {
#if __has_builtin(__builtin_amdgcn_exp2f)
  return __builtin_amdgcn_exp2f(x);
#else
  return exp2f(x);
#endif
}
__device__ __forceinline__ float rcp_hw(float x) {
#if __has_builtin(__builtin_amdgcn_rcpf)
  return __builtin_amdgcn_rcpf(x);
#else
  return 1.0f / x;
#endif
}
__device__ __forceinline__ float elu1(float v) { return v > 0.f ? v : __expf(v) - 1.f; }
__device__ __forceinline__ floatx4 mfma16(short8 a, short8 b, floatx4 c) {
  return __builtin_amdgcn_mfma_f32_16x16x32_bf16(a, b, c, 0, 0, 0);
}

// ws layout (bf16): [0,8192) embT[e][k] (k<40 Wv, else Wp) | [8192,24576) wT0[e][k] | [24576,40960) wT1[e][k]
// Total: 40960 shorts = exactly 81920 B. DO NOT EXCEED (ws_size appears to be 80 KiB).
__global__ void prep_weights(const float* __restrict__ Wv, const float* __restrict__ Wp,
                             const float* __restrict__ w0, const float* __restrict__ w1,
                             short* __restrict__ ws) {
  int idx = blockIdx.x * 256 + threadIdx.x;          // 160 blocks x 256 = 40960
  if (idx < 8192) {
    int e = idx >> 6, k = idx & 63;
    float v = (k < 40) ? Wv[(size_t)k * EMB + e] : Wp[(size_t)(k - 40) * EMB + e];
    ws[idx] = f2bf(v);
  } else if (idx < 24576) {
    int t = idx - 8192; int e = t >> 7, k = t & 127;
    ws[idx] = f2bf(w0[(size_t)k * EMB + e]);
  } else {
    int t = idx - 24576; int e = t >> 7, k = t & 127;
    ws[idx] = f2bf(w1[(size_t)k * EMB + e]);
  }
}

__global__ __launch_bounds__(256, 6) void gnn_fused(
    const float* __restrict__ obs,
    const float* __restrict__ bv, const float* __restrict__ bp,
    const float* __restrict__ as0, const float* __restrict__ ad0,
    const float* __restrict__ as1, const float* __restrict__ ad1,
    const short* __restrict__ wsb,
    float* __restrict__ out)
{
  // 2 item tiles. Per tile: x[32 tok][XSTR] (shorts [0,4352)) aliases 4 hT quarters
  // (wv*1280 + [0,1280)); x and hT never coexist (barrier-fenced).
  __shared__ __align__(16) short s_t[2][TILE];

  const int tid  = threadIdx.x;
  const int lane = tid & 63;
  const int wv   = tid >> 6;      // 0..3 = head; e-rows [32wv,32wv+32); m-tiles {2wv,2wv+1}
  const int col  = lane & 15;
  const int quad = lane >> 4;
  const size_t b0 = (size_t)blockIdx.x * 2;

  const short8  z8 = {0,0,0,0,0,0,0,0};
  const floatx4 fz = {0.f,0.f,0.f,0.f};

  // ---------------- P0: alive masks (wave-uniform SGPR), complement pad, scatter ----------------
  unsigned m32[2]; float invc[2];
  #pragma unroll
  for (int j = 0; j < 2; ++j) {
    const float* orow = obs + (b0 + j) * OBSL;
    float araw = (lane < NTOK) ? orow[1024 + lane] : 0.f;
    bool alv = (lane < NTOK) && (araw >= 0.5f);
    unsigned long long m = __ballot(alv);
    int cnt = __popcll(m);
    unsigned mm = (unsigned)m;
    if (cnt == 0) { mm = 0xFFFFFFFFu; cnt = NTOK; }
    m32[j] = mm; invc[j] = 1.f / (float)cnt;
  }

  {                                             // pad ONLY the scatter complement:
    int idx = tid; int r = -1, k = 0;           // veh rows: cols [40,64); ped rows: cols [0,40)
    if (idx < 48)       { r = (idx * 171) >> 9;  k = 40 + (idx - r * 3) * 8; }       // /3 magic (idx<48)
    else if (idx < 128) { int t2 = idx - 48; int q5 = (t2 * 205) >> 10; r = 16 + q5; k = (t2 - q5 * 5) * 8; } // /5 magic (t2<80)
    if (r >= 0) {
      *(short8*)&s_t[0][r * XSTR + k] = z8;
      *(short8*)&s_t[1][r * XSTR + k] = z8;
    }
  }
  // scatter: 256 float4 per item, 1 iter/wave/item; disjoint from pad -> no barrier between
  #pragma unroll
  for (int j = 0; j < 2; ++j) {
    const float* orow = obs + (b0 + j) * OBSL;
    int i4 = wv * 64 + lane;
    float4 v = *(const float4*)&orow[i4 * 4];
    int r, k;
    if (i4 < 160) { r = (i4 * 205) >> 11;  k = (i4 - r * 10) * 4; }              // /10 magic (i4<160)
    else { int t2 = i4 - 160; int q6 = (t2 * 171) >> 10; r = 16 + q6; k = 40 + (t2 - q6 * 6) * 4; } // /6 magic (t2<96)
    uint2v u; u.x = pk2(v.x, v.y); u.y = pk2(v.z, v.w);
    *(uint2v*)&s_t[j][r * XSTR + k] = u;
  }
  __syncthreads();                              // bar: pad+scatter complete before reads

  // ---------------- P1: embed  D[e][tok] = embT x xin; wave computes e-rows [32wv,32wv+32) ----------------
  {
    short8 Bxin[2][2][2];                       // [j][nt][kt]: full K=64 of x_in, both items
    #pragma unroll
    for (int j = 0; j < 2; ++j)
      #pragma unroll
      for (int nt = 0; nt < 2; ++nt)
        #pragma unroll
        for (int kt = 0; kt < 2; ++kt)
          Bxin[j][nt][kt] = *(const short8*)&s_t[j][(nt * 16 + col) * XSTR + kt * 32 + quad * 8];
    __syncthreads();                            // bar: x_in reads done before embed overwrites cols
    const short* embT = wsb;
    #pragma unroll
    for (int mi = 0; mi < 2; ++mi) {
      const int mtE = wv * 2 + mi;
      short8 A0 = *(const short8*)&embT[(mtE * 16 + col) * 64 + quad * 8];
      short8 A1 = *(const short8*)&embT[(mtE * 16 + col) * 64 + 32 + quad * 8];
      float4 bv4 = *(const float4*)&bv[mtE * 16 + quad * 4];
      float4 bp4 = *(const float4*)&bp[mtE * 16 + quad * 4];
      #pragma unroll
      for (int j = 0; j < 2; ++j)
        #pragma unroll
        for (int nt = 0; nt < 2; ++nt) {
          floatx4 acc = fz;
          acc = mfma16(A0, Bxin[j][nt][0], acc);
          acc = mfma16(A1, Bxin[j][nt][1], acc);
          float4 bb = nt ? bp4 : bv4;
          uint2v u; u.x = pk2(acc[0] + bb.x, acc[1] + bb.y); u.y = pk2(acc[2] + bb.z, acc[3] + bb.w);
          *(uint2v*)&s_t[j][(nt * 16 + col) * XSTR + mtE * 16 + quad * 4] = u;
        }
    }
  }

  // ---------------- GAT layers ----------------
  for (int L = 0; L < 2; ++L) {
    const short* wT  = wsb + 8192 + L * 16384;
    const float* gas = L ? as1 : as0;
    const float* gad = L ? ad1 : ad0;

    __syncthreads();                            // bar: x complete (embed / x_next) before reads

    // hT GEMM, acc-major, both items; A re-read per j (VMEM, keeps regs <=~58)
    floatx4 acc[2][2][2];                       // [j][mi][nt]
    #pragma unroll
    for (int j = 0; j < 2; ++j)
      #pragma unroll
      for (int mi = 0; mi < 2; ++mi) { acc[j][mi][0] = fz; acc[j][mi][1] = fz; }
    #pragma unroll
    for (int kt = 0; kt < 4; ++kt) {
      #pragma unroll
      for (int j = 0; j < 2; ++j) {
        short8 B0 = *(const short8*)&s_t[j][(col) * XSTR + kt * 32 + quad * 8];
        short8 B1 = *(const short8*)&s_t[j][(16 + col) * XSTR + kt * 32 + quad * 8];
        #pragma unroll
        for (int mi = 0; mi < 2; ++mi) {
          const int mt = wv * 2 + mi;
          short8 A = *(const short8*)&wT[(mt * 16 + col) * 128 + kt * 32 + quad * 8];
          acc[j][mi][0] = mfma16(A, B0, acc[j][mi][0]);
          acc[j][mi][1] = mfma16(A, B1, acc[j][mi][1]);
        }
      }
    }

    // alpha partials from accs (own head; VALU work before the barrier)
    float psrc[2][2], pdst[2][2];               // [j][nt]
    #pragma unroll
    for (int j = 0; j < 2; ++j) { psrc[j][0]=0.f; psrc[j][1]=0.f; pdst[j][0]=0.f; pdst[j][1]=0.f; }
    #pragma unroll
    for (int mi = 0; mi < 2; ++mi) {
      const int mt = wv * 2 + mi;
      float4 cs = *(const float4*)&gas[mt * 16 + quad * 4];
      float4 cd = *(const float4*)&gad[mt * 16 + quad * 4];
      #pragma unroll
      for (int j = 0; j < 2; ++j)
        #pragma unroll
        for (int nt = 0; nt < 2; ++nt) {
          floatx4 a = acc[j][mi][nt];
          psrc[j][nt] += a[0]*cs.x + a[1]*cs.y + a[2]*cs.z + a[3]*cs.w;
          pdst[j][nt] += a[0]*cd.x + a[1]*cd.y + a[2]*cd.z + a[3]*cd.w;
        }
    }
    __syncthreads();                            // bar#1: ALL waves' x reads done before hT writes (aliased)

    // hT writes from accs into own quarter of each tile (ushort aliases short -> ordered)
    #pragma unroll
    for (int j = 0; j < 2; ++j)
      #pragma unroll
      for (int mi = 0; mi < 2; ++mi) {
        const int rowloc = mi * 16 + quad * 4;  // e-local row within quarter
        #pragma unroll
        for (int nt = 0; nt < 2; ++nt) {
          floatx4 a = acc[j][mi][nt];
          unsigned u01 = pk2(a[0], a[1]);
          unsigned u23 = pk2(a[2], a[3]);
          unsigned short* hrow = (unsigned short*)&s_t[j][wv * 1280 + rowloc * HSTR + nt * 16 + col];
          hrow[0]        = (unsigned short)u01;
          hrow[HSTR]     = (unsigned short)(u01 >> 16);
          hrow[2 * HSTR] = (unsigned short)u23;
          hrow[3 * HSTR] = (unsigned short)(u23 >> 16);
        }
      }

    // full per-token alpha in every lane (token = nt*16 + col), scaled to exp2 domain
    #pragma unroll
    for (int j = 0; j < 2; ++j)
      #pragma unroll
      for (int nt = 0; nt < 2; ++nt) {
        float vs = psrc[j][nt]; vs += __shfl_xor(vs, 16); vs += __shfl_xor(vs, 32);
        psrc[j][nt] = vs * 1.44269504088896340736f;
        float vd = pdst[j][nt]; vd += __shfl_xor(vd, 16); vd += __shfl_xor(vd, 32);
        pdst[j][nt] = vd * 1.44269504088896340736f;
      }

    // softmax (own head) in PV B-frag layout: lane owns (i = ii*16+col, key = quad*8+jj)
    short8 pf[2][2];                            // [j][ii]
    #pragma unroll
    for (int j = 0; j < 2; ++j) {
      float vsel = (quad >> 1) ? pdst[j][1] : pdst[j][0];
      float ad8[8];
      #pragma unroll
      for (int jj = 0; jj < 8; ++jj) {
        float v = __shfl(vsel, ((quad >> 1) << 5) + ((quad & 1) << 3) + jj);
        bool alive = (m32[j] >> (quad * 8 + jj)) & 1u;     // mask test, no shuffle
        ad8[jj] = alive ? v : -1e30f;                      // dead keys -> exp2 -> 0
      }
      #pragma unroll
      for (int ii = 0; ii < 2; ++ii) {
        float ai = psrc[j][ii];
        float ev[8]; float sum = 0.f;
        #pragma unroll
        for (int jj = 0; jj < 8; ++jj) {
          float e = ai + ad8[jj];
          e = fmaxf(e, 0.2f * e);                          // leaky-relu (commutes with log2e scale)
          float p = exp2_hw(e);
          ev[jj] = p; sum += p;
        }
        sum += __shfl_xor(sum, 16);
        sum += __shfl_xor(sum, 32);
        float inv = rcp_hw(sum);
        union { unsigned u4[4]; short8 s; } pu;
        #pragma unroll
        for (int p2 = 0; p2 < 4; ++p2) pu.u4[p2] = pk2(ev[2*p2] * inv, ev[2*p2+1] * inv);
        pf[j][ii] = pu.s;
      }
    }

    // PV A-frags from own (wave-private) hT quarters, BOTH items, before barrier
    short8 Ah[2][2];                            // [j][mt2]
    #pragma unroll
    for (int j = 0; j < 2; ++j)
      #pragma unroll
      for (int mt2 = 0; mt2 < 2; ++mt2)
        Ah[j][mt2] = *(const short8*)&s_t[j][wv * 1280 + (mt2 * 16 + col) * HSTR + quad * 8];
    if (L == 0) __syncthreads();                // bar#2: hT reads done before x_next writes (aliased)

    #pragma unroll
    for (int j = 0; j < 2; ++j) {
      #pragma unroll
      for (int mt2 = 0; mt2 < 2; ++mt2) {
        floatx4 po[2];
        #pragma unroll
        for (int nt = 0; nt < 2; ++nt) {
          po[nt] = mfma16(Ah[j][mt2], pf[j][nt], fz);
        }
        const int ecol = wv * 32 + mt2 * 16 + quad * 4;  // global e
        if (L == 0) {
          #pragma unroll
          for (int nt = 0; nt < 2; ++nt) {
            uint2v u;
            u.x = pk2(elu1(po[nt][0]), elu1(po[nt][1]));
            u.y = pk2(elu1(po[nt][2]), elu1(po[nt][3]));
            *(uint2v*)&s_t[j][(nt * 16 + col) * XSTR + ecol] = u;
          }
        } else {
          float aI0 = ((m32[j] >> col) & 1u) ? 1.f : 0.f;        // alive of token col
          float aI1 = ((m32[j] >> (16 + col)) & 1u) ? 1.f : 0.f; // alive of token 16+col
          #pragma unroll
          for (int r = 0; r < 4; ++r) {
            float s = elu1(po[0][r]) * aI0 + elu1(po[1][r]) * aI1;
            s += __shfl_xor(s, 1); s += __shfl_xor(s, 2);
            s += __shfl_xor(s, 4); s += __shfl_xor(s, 8);
            if (col == 0) out[(b0 + j) * EMB + ecol + r] = s * invc[j];  // direct store (proven path)
          }
        }
      }
    }
  }
}

extern "C" void kernel_launch(void* const* d_in, const int* in_sizes, int n_in,
                              void* d_out, int out_size, void* d_ws, size_t ws_size,
                              hipStream_t stream) {
  const float* obs = (const float*)d_in[0];
  const float* Wv  = (const float*)d_in[1];
  const float* bv  = (const float*)d_in[2];
  const float* Wp  = (const float*)d_in[3];
  const float* bp  = (const float*)d_in[4];
  const float* w0  = (const float*)d_in[5];
  const float* as0 = (const float*)d_in[6];
  const float* ad0 = (const float*)d_in[7];
  const float* w1  = (const float*)d_in[8];
  const float* as1 = (const float*)d_in[9];
  const float* ad1 = (const float*)d_in[10];
  float* out = (float*)d_out;
  short* wsb = (short*)d_ws;                      // uses exactly 80 KiB

  int Bn = in_sizes[0] / OBSL;                    // 4096
  prep_weights<<<160, 256, 0, stream>>>(Wv, Wp, w0, w1, wsb);
  gnn_fused<<<Bn / 2, 256, 0, stream>>>(obs, bv, bp, as0, ad0, as1, ad1, wsb, out);
}